// Round 2
// baseline (232.653 us; speedup 1.0000x reference)
//
#include <hip/hip_runtime.h>
#include <stdint.h>

#define IN_F 1024
#define OUT_F 1024
#define SCALING 0.25f
#define TILE_ROWS 16
#define BLOCK 256

// LoRA rank-4 streaming kernel. Block = 256 threads = 4 waves, 16 rows/tile.
//
// Wait-point-minimized structure: with 8192 waves (~whole machine) resident,
// wall time is governed by the number of SERIALIZED vmcnt wait-points per
// wave, not per-wave compute. So each wave issues ALL its phase-1 loads in
// one burst (16 x-float4 covering its 4 rows + 16 A-float4 = 8 KB), takes a
// single vmcnt cascade, computes all 16 (row,rank) partials with independent
// FMA chains, then does ONE batched 6-stage butterfly (16 independent shfls
// per stage). B-fragment loads are issued before the butterfly so their
// latency hides under it + the barrier.
//
// __launch_bounds__(256,3) grants ~168 VGPRs so the A-fragment (64), the
// 4-row x burst (64) and 16 accumulators can ALL stay register-resident —
// R1's build at default bounds got squeezed to 68 VGPRs and the compiler
// re-loaded A per row, adding a near-vmcnt(0) wait every row.
__global__ __launch_bounds__(BLOCK, 3) void lora_tile(
    const float* __restrict__ x, const float* __restrict__ A,
    const float* __restrict__ B, float* __restrict__ out, int nrows) {
  __shared__ float4 hf[TILE_ROWS];  // 256 B: final h per row

  const int t = threadIdx.x;
  const int lane = t & 63;
  const int wave = t >> 6;
  const int row0 = blockIdx.x * TILE_ROWS;
  if (row0 >= nrows) return;

  const float4* __restrict__ x4 =
      (const float4*)(x + (size_t)(row0 + wave * 4) * IN_F);
  const float4* __restrict__ A4 = (const float4*)A;

  // ---- Phase 1 load burst: 32 independent float4 loads, zero waits. ----
  // x: lane owns f4-columns {lane + 64k}; rows wave*4 .. wave*4+3.
  float4 xr[4][4];
#pragma unroll
  for (int i = 0; i < 4; ++i)
#pragma unroll
    for (int k = 0; k < 4; ++k) xr[i][k] = x4[i * 256 + lane + 64 * k];

  // A: same f4-columns, ranks 0..3. k-outer so the first FMA group's
  // operands are the earliest A loads (deeper vmcnt cascade).
  float4 a[4][4];  // [r][k]
#pragma unroll
  for (int k = 0; k < 4; ++k)
#pragma unroll
    for (int r = 0; r < 4; ++r) a[r][k] = A4[r * 256 + lane + 64 * k];

  // 16 independent accumulator chains: p[row][rank].
  float p[4][4];
#pragma unroll
  for (int i = 0; i < 4; ++i)
#pragma unroll
    for (int r = 0; r < 4; ++r) p[i][r] = 0.f;

#pragma unroll
  for (int i = 0; i < 4; ++i)
#pragma unroll
    for (int k = 0; k < 4; ++k) {
      const float4 xv = xr[i][k];  // static index after unroll
#pragma unroll
      for (int r = 0; r < 4; ++r)
        p[i][r] += xv.x * a[r][k].x + xv.y * a[r][k].y + xv.z * a[r][k].z +
                   xv.w * a[r][k].w;
    }

  // Issue B fragment now — latency hides under the butterfly + barrier.
  // (x regs are dead here, so no pressure stacking.)
  const float4* __restrict__ B4 = (const float4*)B;
  const float4 bf0 = B4[4 * t + 0];
  const float4 bf1 = B4[4 * t + 1];
  const float4 bf2 = B4[4 * t + 2];
  const float4 bf3 = B4[4 * t + 3];

  // ONE batched butterfly: 6 stages, 16 independent shfls per stage
  // (vs 4 serial 6-stage chains in R1).
#pragma unroll
  for (int off = 1; off < 64; off <<= 1)
#pragma unroll
    for (int i = 0; i < 4; ++i)
#pragma unroll
      for (int r = 0; r < 4; ++r) p[i][r] += __shfl_xor(p[i][r], off, 64);

  if (lane == 0) {
#pragma unroll
    for (int i = 0; i < 4; ++i)
      hf[wave * 4 + i] =
          make_float4(p[i][0] * SCALING, p[i][1] * SCALING, p[i][2] * SCALING,
                      p[i][3] * SCALING);
  }
  __syncthreads();

  // ---- Phase 2: expand 16 rows x 1024 cols, coalesced float4 stores. ----
  float4* __restrict__ out4 = (float4*)out;
#pragma unroll
  for (int r = 0; r < TILE_ROWS; ++r) {
    const float4 h = hf[r];  // same addr all lanes -> LDS broadcast
    float4 res;
    res.x = h.x * bf0.x + h.y * bf0.y + h.z * bf0.z + h.w * bf0.w;
    res.y = h.x * bf1.x + h.y * bf1.y + h.z * bf1.z + h.w * bf1.w;
    res.z = h.x * bf2.x + h.y * bf2.y + h.z * bf2.z + h.w * bf2.w;
    res.w = h.x * bf3.x + h.y * bf3.y + h.z * bf3.z + h.w * bf3.w;
    out4[(size_t)(row0 + r) * (OUT_F / 4) + t] = res;
  }
}

extern "C" void kernel_launch(void* const* d_in, const int* in_sizes, int n_in,
                              void* d_out, int out_size, void* d_ws,
                              size_t ws_size, hipStream_t stream) {
  const float* x = (const float*)d_in[0];
  const float* A = (const float*)d_in[1];
  const float* B = (const float*)d_in[2];
  float* out = (float*)d_out;

  const int nrows = in_sizes[0] / IN_F;                    // 32768
  const int blocks = (nrows + TILE_ROWS - 1) / TILE_ROWS;  // 2048
  lora_tile<<<blocks, BLOCK, 0, stream>>>(x, A, B, out, nrows);
}